// Round 1
// baseline (621.126 us; speedup 1.0000x reference)
//
#include <hip/hip_runtime.h>
#include <hip/hip_bf16.h>
#include <stdint.h>

// Problem constants
#define BATCH 32768
#define PP 24
#define CIN 64
#define COUT 64
#define NORB 24
#define KDIM (PP * CIN)   // 1536
#define NDIM (PP * COUT)  // 1536

// GEMM tiling
#define BM 128
#define BN 128
#define BK 64
#define NKT (KDIM / BK)   // 24

typedef __attribute__((ext_vector_type(8))) short short8;
typedef __attribute__((ext_vector_type(4))) float f32x4;

// ---------------------------------------------------------------------------
// Kernel 1: gather weight into KmatT[col=(i*64+o)][k=(j*64+c)] = W[o,c,po[i,j]]
// KmatT is row-major (NDIM x KDIM) bf16, lives in d_ws (4.5 MiB).
// ---------------------------------------------------------------------------
__global__ __launch_bounds__(256) void build_kmat(
    const float* __restrict__ weight, const int* __restrict__ po,
    __bf16* __restrict__ kmatT) {
  int col = blockIdx.x * 256 + threadIdx.x;  // k index: j*64+c
  int row = blockIdx.y;                      // n index: i*64+o
  int i = row >> 6, o = row & 63;
  int j = col >> 6, c = col & 63;
  int orbit = po[i * PP + j];
  float v = weight[(o * CIN + c) * NORB + orbit];
  kmatT[(size_t)row * KDIM + col] = (__bf16)v;
}

// ---------------------------------------------------------------------------
// Kernel 2: GEMM  out[M=32768][N=1536] = X[M][K=1536] * KmatT[N][K]^T + bias
// 128x128 tile, BK=64, 4 waves (2x2), 16x16x32 bf16 MFMA, 4x4 frags/wave.
// A: f32 global -> regs -> cvt bf16 -> swizzled LDS write.
// B: bf16 global_load_lds width=16, source pre-swizzled (rule 21).
// LDS XOR swizzle: chunk' = chunk ^ (row & 7)  (16B chunks, 128B rows).
// ---------------------------------------------------------------------------
__device__ inline void gload_lds16(const void* g, void* l) {
  __builtin_amdgcn_global_load_lds(
      (const __attribute__((address_space(1))) unsigned int*)g,
      (__attribute__((address_space(3))) unsigned int*)l, 16, 0, 0);
}

__global__ __launch_bounds__(256, 2) void gemm_kernel(
    const float* __restrict__ X, const __bf16* __restrict__ KT,
    const float* __restrict__ bias, float* __restrict__ out) {
  __shared__ __align__(16) short Alds[BM * BK];  // [r][swz chunk], 16 KB
  __shared__ __align__(16) short Blds[BN * BK];  // [c][swz chunk], 16 KB

  int tid = threadIdx.x;
  int bid = blockIdx.x;
  int nwg = gridDim.x;          // 3072 (divisible by 8)
  int cpx = nwg >> 3;           // 384 blocks per XCD
  int swz = (bid & 7) * cpx + (bid >> 3);
  // group blocks into bands of 4 M-tiles x all 12 N-tiles for L2 A-reuse
  int group = swz / 48;
  int within = swz - group * 48;
  int nt = within >> 2;                 // 0..11
  int mt = (group << 2) | (within & 3); // 0..255
  int b0 = mt * BM;
  int n0 = nt * BN;

  int lane = tid & 63;
  int wave = tid >> 6;
  int wm = wave >> 1, wn = wave & 1;
  int l16 = lane >> 4, lm = lane & 15;

  f32x4 acc[4][4] = {};

  // A staging map: thread -> (row ar, half ah); each stages 32 f32 = 128B
  int ar = tid & 127, ah = tid >> 7;
  const float* asrc_base = X + (size_t)(b0 + ar) * KDIM + ah * 32;

  for (int kt = 0; kt < NKT; ++kt) {
    // --- A global loads (f32, no LDS dep) issued before the barrier ---
    const float4* asrc = (const float4*)(asrc_base + kt * BK);
    float4 f[8];
#pragma unroll
    for (int q = 0; q < 8; ++q) f[q] = asrc[q];

    if (kt) __syncthreads();  // prev tile's readers done before overwrite

    // --- B stage: global_load_lds, 4x 1KB per wave, source pre-swizzled ---
#pragma unroll
    for (int q = 0; q < 4; ++q) {
      int rowg = (wave * 4 + q) * 8 + (lane >> 3);  // local B row (N-col)
      int s = lane & 7;                             // physical 16B chunk
      int chl = s ^ (rowg & 7);                     // logical chunk fetched
      const __bf16* g = KT + (size_t)(n0 + rowg) * KDIM + kt * BK + chl * 8;
      gload_lds16((const void*)g, (void*)&Blds[(wave * 4 + q) * 512]);
    }

    // --- A convert f32->bf16 + swizzled ds_write_b128 ---
#pragma unroll
    for (int q = 0; q < 4; ++q) {
      union { __bf16 h[8]; short8 v; } pk;
      float4 a0 = f[2 * q], a1 = f[2 * q + 1];
      pk.h[0] = (__bf16)a0.x; pk.h[1] = (__bf16)a0.y;
      pk.h[2] = (__bf16)a0.z; pk.h[3] = (__bf16)a0.w;
      pk.h[4] = (__bf16)a1.x; pk.h[5] = (__bf16)a1.y;
      pk.h[6] = (__bf16)a1.z; pk.h[7] = (__bf16)a1.w;
      int sch = (ah * 4 + q) ^ (ar & 7);
      *(short8*)&Alds[ar * 64 + sch * 8] = pk.v;
    }

    __syncthreads();

    // --- compute: 2 k-steps x 4x4 frags = 32 MFMA, 16 ds_read_b128 ---
#pragma unroll
    for (int ks = 0; ks < 2; ++ks) {
      short8 av[4], bv[4];
#pragma unroll
      for (int mf = 0; mf < 4; ++mf) {
        int r = wm * 64 + mf * 16 + lm;
        int ch = (ks * 4 + l16) ^ (r & 7);
        av[mf] = *(const short8*)&Alds[r * 64 + ch * 8];
      }
#pragma unroll
      for (int nf = 0; nf < 4; ++nf) {
        int c = wn * 64 + nf * 16 + lm;
        int ch = (ks * 4 + l16) ^ (c & 7);
        bv[nf] = *(const short8*)&Blds[c * 64 + ch * 8];
      }
#pragma unroll
      for (int mf = 0; mf < 4; ++mf)
#pragma unroll
        for (int nf = 0; nf < 4; ++nf)
          acc[mf][nf] = __builtin_amdgcn_mfma_f32_16x16x32_bf16(
              av[mf], bv[nf], acc[mf][nf], 0, 0, 0);
    }
  }

  // --- epilogue: C/D layout col=lane&15, row=(lane>>4)*4+reg ---
  int r0 = b0 + wm * 64 + l16 * 4;
  int c0 = n0 + wn * 64 + lm;
#pragma unroll
  for (int nf = 0; nf < 4; ++nf) {
    int col = c0 + nf * 16;
    float bvv = bias[col & 63];
#pragma unroll
    for (int mf = 0; mf < 4; ++mf) {
#pragma unroll
      for (int j = 0; j < 4; ++j) {
        out[(size_t)(r0 + mf * 16 + j) * NDIM + col] = acc[mf][nf][j] + bvv;
      }
    }
  }
}

extern "C" void kernel_launch(void* const* d_in, const int* in_sizes, int n_in,
                              void* d_out, int out_size, void* d_ws, size_t ws_size,
                              hipStream_t stream) {
  const float* x = (const float*)d_in[0];
  const float* w = (const float*)d_in[1];
  const float* bias = (const float*)d_in[2];
  const int* po = (const int*)d_in[3];
  float* out = (float*)d_out;
  __bf16* kmatT = (__bf16*)d_ws;  // 1536*1536*2 = 4.5 MiB

  build_kmat<<<dim3(KDIM / 256, NDIM), 256, 0, stream>>>(w, po, kmatT);
  gemm_kernel<<<dim3((BATCH / BM) * (NDIM / BN)), 256, 0, stream>>>(
      x, kmatT, bias, out);
}

// Round 3
// 493.099 us; speedup vs baseline: 1.2596x; 1.2596x over previous
//
#include <hip/hip_runtime.h>
#include <hip/hip_bf16.h>
#include <stdint.h>

// Problem constants
#define BATCH 32768
#define PP 24
#define CIN 64
#define COUT 64
#define NORB 24
#define KDIM 1536
#define NDIM 1536
#define NKT 24  // K-tiles of 64

typedef __attribute__((ext_vector_type(8))) short short8;
typedef __attribute__((ext_vector_type(4))) float f32x4;

__device__ inline void gload_lds16(const void* g, void* l) {
  __builtin_amdgcn_global_load_lds(
      (const __attribute__((address_space(1))) unsigned int*)g,
      (__attribute__((address_space(3))) unsigned int*)l, 16, 0, 0);
}

// ---------------------------------------------------------------------------
// Kernel 1: KmatT[row=(i*64+o)][k=(j*64+c)] = W[o,c,po[i,j]]   (bf16, 4.5 MiB)
// 1536 blocks x 192 threads; each thread emits 8 contiguous k (one j-block).
// ---------------------------------------------------------------------------
__global__ void build_kmat(const float* __restrict__ weight,
                           const int* __restrict__ po,
                           __bf16* __restrict__ kmatT) {
  int row = blockIdx.x;        // i*64+o
  int col0 = threadIdx.x * 8;  // k base; all 8 share the same j
  int i = row >> 6, o = row & 63;
  int j = col0 >> 6;
  int orbit = po[i * PP + j];
  union { __bf16 h[8]; short8 v; } u;
  const float* wb = &weight[(o * CIN + (col0 & 63)) * NORB + orbit];
#pragma unroll
  for (int c = 0; c < 8; ++c) u.h[c] = (__bf16)wb[c * NORB];
  *(short8*)&kmatT[(size_t)row * KDIM + col0] = u.v;
}

// ---------------------------------------------------------------------------
// Kernel 2: X (f32) -> Xbf (bf16), 8 elems/thread
// ---------------------------------------------------------------------------
__global__ __launch_bounds__(256) void convert_x(const float* __restrict__ x,
                                                 __bf16* __restrict__ xb,
                                                 int n8) {
  int idx = blockIdx.x * 256 + threadIdx.x;
  if (idx >= n8) return;
  const float4* p = (const float4*)x + (size_t)idx * 2;
  float4 a = p[0], b = p[1];
  union { __bf16 h[8]; short8 v; } u;
  u.h[0] = (__bf16)a.x; u.h[1] = (__bf16)a.y;
  u.h[2] = (__bf16)a.z; u.h[3] = (__bf16)a.w;
  u.h[4] = (__bf16)b.x; u.h[5] = (__bf16)b.y;
  u.h[6] = (__bf16)b.z; u.h[7] = (__bf16)b.w;
  ((short8*)xb)[idx] = u.v;
}

// ---------------------------------------------------------------------------
// Kernel 3: 8-phase 256x256 GEMM.  out[32768][1536] = Xbf * KmatT^T + bias
// 8 waves (2M x 4N), BK=64, LDS 128 KiB (2 buf x (A 32K + B 32K)).
// Phases per K-tile: (mh,nh) = (0,0),(0,1),(1,0),(1,1); 16 MFMA each.
// Stage stream (tile t): P0->(t+1).B1  P1->(t+1).A1  P2->(t+2).A0  P3->(t+2).B0
// Region death: A-half mh dies at phase (mh,1); B-half nh dies at (1,nh).
// vmcnt ladder (loads, 2/stage/wave): steady 8,8,8,-; final tile 4,2,0,-.
// Swizzle: 16B chunk ^= (row&7), source pre-swizzled for global_load_lds.
// ---------------------------------------------------------------------------
#define VM8 asm volatile("s_waitcnt vmcnt(8)" ::: "memory")
#define VM4 asm volatile("s_waitcnt vmcnt(4)" ::: "memory")
#define VM2 asm volatile("s_waitcnt vmcnt(2)" ::: "memory")
#define VM0 asm volatile("s_waitcnt vmcnt(0)" ::: "memory")
#define VMX ((void)0)

#define PHASE(buf, mh, nh, VMOP, STAGE_STMT)                                   \
  do {                                                                         \
    VMOP;                                                                      \
    __builtin_amdgcn_s_barrier();                                              \
    short8 av[4][2], bv[2][2];                                                 \
    _Pragma("unroll") for (int mf = 0; mf < 4; ++mf) {                         \
      int r = wm * 128 + (mh) * 64 + mf * 16 + lm;                             \
      const char* ab = lds + (buf) * 65536 + r * 128;                          \
      av[mf][0] = *(const short8*)(ab + ch0 * 16);                             \
      av[mf][1] = *(const short8*)(ab + ch1 * 16);                             \
    }                                                                          \
    _Pragma("unroll") for (int nf = 0; nf < 2; ++nf) {                         \
      int c = wn * 64 + (nh) * 32 + nf * 16 + lm;                              \
      const char* bb = lds + (buf) * 65536 + 32768 + c * 128;                  \
      bv[nf][0] = *(const short8*)(bb + ch0 * 16);                             \
      bv[nf][1] = *(const short8*)(bb + ch1 * 16);                             \
    }                                                                          \
    STAGE_STMT;                                                                \
    __builtin_amdgcn_s_barrier();                                              \
    __builtin_amdgcn_s_setprio(1);                                             \
    _Pragma("unroll") for (int ks = 0; ks < 2; ++ks)                           \
    _Pragma("unroll") for (int mf = 0; mf < 4; ++mf)                           \
    _Pragma("unroll") for (int nf = 0; nf < 2; ++nf)                           \
      acc[(mh) * 4 + mf][(nh) * 2 + nf] =                                      \
          __builtin_amdgcn_mfma_f32_16x16x32_bf16(                             \
              av[mf][ks], bv[nf][ks], acc[(mh) * 4 + mf][(nh) * 2 + nf],       \
              0, 0, 0);                                                        \
    __builtin_amdgcn_s_setprio(0);                                             \
  } while (0)

__global__ __launch_bounds__(512, 2) void gemm8(
    const __bf16* __restrict__ XBF, const __bf16* __restrict__ KT,
    const float* __restrict__ bias, float* __restrict__ out) {
  __shared__ __align__(16) char lds[131072];

  int tid = threadIdx.x;
  int lane = tid & 63, wave = tid >> 6;
  int wm = wave >> 2, wn = wave & 3;
  int lm = lane & 15, l16 = lane >> 4;
  int ch0 = l16 ^ (lm & 7), ch1 = ch0 ^ 4;

  // XCD swizzle (768 blocks % 8 == 0), then 6 consecutive share an M-panel.
  int bid = blockIdx.x;
  int s = (bid & 7) * 96 + (bid >> 3);
  int mt = s / 6, nt = s - mt * 6;
  int m0 = mt * 256, n0 = nt * 256;

  int lr = lane >> 3;                 // 0..7
  int koff = ((lane & 7) ^ lr) * 8;   // pre-swizzled k element offset

  // stage one A half-tile (rows with bit6==h) of K-tile kt into buffer buf
  auto stageA = [&](int buf, int h, int kt) {
#pragma unroll
    for (int q = 0; q < 2; ++q) {
      int r = q * 128 + h * 64 + wave * 8 + lr;
      const __bf16* g = XBF + (size_t)(m0 + r) * KDIM + kt * 64 + koff;
      char* l = lds + buf * 65536 + q * 16384 + h * 8192 + wave * 1024;
      gload_lds16((const void*)g, (void*)l);
    }
  };
  // stage one B half-tile (cols with bit5==nh) of K-tile kt into buffer buf
  auto stageB = [&](int buf, int nh, int kt) {
#pragma unroll
    for (int q = 0; q < 2; ++q) {
      int seg = wave * 2 + q;
      int g4 = seg >> 2, b4 = seg & 3;
      int c = nh * 32 + 64 * g4 + b4 * 8 + lr;
      const __bf16* g = KT + (size_t)(n0 + c) * KDIM + kt * 64 + koff;
      char* l = lds + buf * 65536 + 32768 + (nh * 32 + 64 * g4) * 128 +
                b4 * 1024;
      gload_lds16((const void*)g, (void*)l);
    }
  };

  f32x4 acc[8][4] = {};

  // prologue: 6 half-tiles in stream order -> 12 loads/wave in flight
  stageA(0, 0, 0); stageB(0, 0, 0); stageB(0, 1, 0); stageA(0, 1, 0);
  stageA(1, 0, 1); stageB(1, 0, 1);

  for (int t = 0; t < NKT - 1; ++t) {
    int cur = t & 1, nb = cur ^ 1;
    PHASE(cur, 0, 0, VM8, { stageB(nb, 1, t + 1); });
    PHASE(cur, 0, 1, VM8, { stageA(nb, 1, t + 1); });
    PHASE(cur, 1, 0, VM8, { if (t + 2 < NKT) stageA(cur, 0, t + 2); });
    PHASE(cur, 1, 1, VMX, { if (t + 2 < NKT) stageB(cur, 0, t + 2); });
  }
  // final tile (t = NKT-1 = 23, buffer 1): drain ladder
  PHASE(1, 0, 0, VM4, VMX);
  PHASE(1, 0, 1, VM2, VMX);
  PHASE(1, 1, 0, VM0, VMX);
  PHASE(1, 1, 1, VMX, VMX);

  // epilogue: C/D layout col=lane&15, row=(lane>>4)*4+reg
  int r0 = m0 + wm * 128 + l16 * 4;
  int c0 = n0 + wn * 64 + lm;
#pragma unroll
  for (int NF = 0; NF < 4; ++NF) {
    int col = c0 + NF * 16;
    float bvv = bias[col & 63];
#pragma unroll
    for (int MF = 0; MF < 8; ++MF) {
#pragma unroll
      for (int j = 0; j < 4; ++j) {
        out[(size_t)(r0 + MF * 16 + j) * NDIM + col] = acc[MF][NF][j] + bvv;
      }
    }
  }
}

// ---------------------------------------------------------------------------
// Fallback GEMM (round-1, 128x128, f32 X) if ws is too small for Xbf
// ---------------------------------------------------------------------------
__global__ __launch_bounds__(256, 2) void gemm_fallback(
    const float* __restrict__ X, const __bf16* __restrict__ KT,
    const float* __restrict__ bias, float* __restrict__ out) {
  __shared__ __align__(16) short Alds[128 * 64];
  __shared__ __align__(16) short Blds[128 * 64];

  int tid = threadIdx.x;
  int bid = blockIdx.x;
  int cpx = gridDim.x >> 3;
  int swz = (bid & 7) * cpx + (bid >> 3);
  int group = swz / 48;
  int within = swz - group * 48;
  int nt = within >> 2;
  int mt = (group << 2) | (within & 3);
  int b0 = mt * 128, n0 = nt * 128;

  int lane = tid & 63, wave = tid >> 6;
  int wm = wave >> 1, wn = wave & 1;
  int l16 = lane >> 4, lm = lane & 15;

  f32x4 acc[4][4] = {};
  int ar = tid & 127, ah = tid >> 7;
  const float* asrc_base = X + (size_t)(b0 + ar) * KDIM + ah * 32;

  for (int kt = 0; kt < NKT; ++kt) {
    const float4* asrc = (const float4*)(asrc_base + kt * 64);
    float4 f[8];
#pragma unroll
    for (int q = 0; q < 8; ++q) f[q] = asrc[q];
    if (kt) __syncthreads();
#pragma unroll
    for (int q = 0; q < 4; ++q) {
      int rowg = (wave * 4 + q) * 8 + (lane >> 3);
      int chl = (lane & 7) ^ (rowg & 7);
      const __bf16* g = KT + (size_t)(n0 + rowg) * KDIM + kt * 64 + chl * 8;
      gload_lds16((const void*)g, (void*)&Blds[(wave * 4 + q) * 512]);
    }
#pragma unroll
    for (int q = 0; q < 4; ++q) {
      union { __bf16 h[8]; short8 v; } pk;
      float4 a0 = f[2 * q], a1 = f[2 * q + 1];
      pk.h[0] = (__bf16)a0.x; pk.h[1] = (__bf16)a0.y;
      pk.h[2] = (__bf16)a0.z; pk.h[3] = (__bf16)a0.w;
      pk.h[4] = (__bf16)a1.x; pk.h[5] = (__bf16)a1.y;
      pk.h[6] = (__bf16)a1.z; pk.h[7] = (__bf16)a1.w;
      int sch = (ah * 4 + q) ^ (ar & 7);
      *(short8*)&Alds[ar * 64 + sch * 8] = pk.v;
    }
    __syncthreads();
#pragma unroll
    for (int ks = 0; ks < 2; ++ks) {
      short8 av[4], bv[4];
#pragma unroll
      for (int mf = 0; mf < 4; ++mf) {
        int r = wm * 64 + mf * 16 + lm;
        int ch = (ks * 4 + l16) ^ (r & 7);
        av[mf] = *(const short8*)&Alds[r * 64 + ch * 8];
      }
#pragma unroll
      for (int nf = 0; nf < 4; ++nf) {
        int c = wn * 64 + nf * 16 + lm;
        int ch = (ks * 4 + l16) ^ (c & 7);
        bv[nf] = *(const short8*)&Blds[c * 64 + ch * 8];
      }
#pragma unroll
      for (int mf = 0; mf < 4; ++mf)
#pragma unroll
        for (int nf = 0; nf < 4; ++nf)
          acc[mf][nf] = __builtin_amdgcn_mfma_f32_16x16x32_bf16(
              av[mf], bv[nf], acc[mf][nf], 0, 0, 0);
    }
  }

  int r0 = b0 + wm * 64 + l16 * 4;
  int c0 = n0 + wn * 64 + lm;
#pragma unroll
  for (int nf = 0; nf < 4; ++nf) {
    int col = c0 + nf * 16;
    float bvv = bias[col & 63];
#pragma unroll
    for (int mf = 0; mf < 4; ++mf)
#pragma unroll
      for (int j = 0; j < 4; ++j)
        out[(size_t)(r0 + mf * 16 + j) * NDIM + col] = acc[mf][nf][j] + bvv;
  }
}

extern "C" void kernel_launch(void* const* d_in, const int* in_sizes, int n_in,
                              void* d_out, int out_size, void* d_ws,
                              size_t ws_size, hipStream_t stream) {
  const float* x = (const float*)d_in[0];
  const float* w = (const float*)d_in[1];
  const float* bias = (const float*)d_in[2];
  const int* po = (const int*)d_in[3];
  float* out = (float*)d_out;

  const size_t KMAT_BYTES = (size_t)NDIM * KDIM * 2;          // 4.5 MiB
  const size_t XBF_BYTES = (size_t)BATCH * KDIM * 2;          // 96 MiB
  __bf16* kmatT = (__bf16*)d_ws;

  build_kmat<<<dim3(NDIM), dim3(KDIM / 8), 0, stream>>>(w, po, kmatT);

  if (ws_size >= KMAT_BYTES + XBF_BYTES) {
    __bf16* xbf = (__bf16*)((char*)d_ws + KMAT_BYTES);
    int n8 = BATCH * KDIM / 8;
    convert_x<<<dim3(n8 / 256), dim3(256), 0, stream>>>(x, xbf, n8);
    gemm8<<<dim3((BATCH / 256) * (NDIM / 256)), dim3(512), 0, stream>>>(
        xbf, kmatT, bias, out);
  } else {
    gemm_fallback<<<dim3((BATCH / 128) * (NDIM / 128)), dim3(256), 0, stream>>>(
        x, kmatT, bias, out);
  }
}